// Round 1
// baseline (1231.535 us; speedup 1.0000x reference)
//
#include <hip/hip_runtime.h>

#define BB 128
#define NN 512
#define DD 128

// ---------------- kernel 1: h -> normalized hn ----------------
__global__ __launch_bounds__(256) void hn_kernel(const float* __restrict__ h,
                                                 const float* __restrict__ W0,
                                                 const float* __restrict__ W1,
                                                 float* __restrict__ hn) {
    int wave = (int)((blockIdx.x * blockDim.x + threadIdx.x) >> 6);  // 0..B*N-1
    int lane = threadIdx.x & 63;
    const float2* h2 = (const float2*)(h + (size_t)wave * DD);
    float2 w0 = ((const float2*)W0)[lane];
    float2 w1 = ((const float2*)W1)[lane];
    float2 x = h2[lane];
    float p0 = fmaxf(x.x * w0.x, 0.0f) * w1.x;
    float p1 = fmaxf(x.y * w0.y, 0.0f) * w1.y;
    float ss = p0 * p0 + p1 * p1;
#pragma unroll
    for (int m = 32; m; m >>= 1) ss += __shfl_xor(ss, m);
    float inv = 1.0f / (sqrtf(ss) + 1e-12f);
    float2 o;
    o.x = p0 * inv;
    o.y = p1 * inv;
    ((float2*)(hn + (size_t)wave * DD))[lane] = o;
}

// ---------------- kernel 2: sim = (hn hn^T + eye) * mask2 -> d_out --------
#define KC 32
__global__ __launch_bounds__(256) void sim_kernel(const float* __restrict__ hn,
                                                  const int* __restrict__ lengths,
                                                  float* __restrict__ sim) {
    __shared__ float As[KC][132];
    __shared__ float Bs[KC][132];
    int b = blockIdx.z;
    int r0 = blockIdx.y * 128, c0 = blockIdx.x * 128;
    int len = max(lengths[b], 1);
    const float* base = hn + (size_t)b * NN * DD;
    int tid = threadIdx.x;
    int lr = tid >> 3;
    int lk = (tid & 7) << 2;
    int tx = tid & 15, ty = tid >> 4;
    float acc[8][8] = {};

    for (int kc = 0; kc < DD; kc += KC) {
#pragma unroll
        for (int rr = 0; rr < 128; rr += 32) {
            float4 a = *(const float4*)(base + (size_t)(r0 + lr + rr) * DD + kc + lk);
            As[lk + 0][lr + rr] = a.x; As[lk + 1][lr + rr] = a.y;
            As[lk + 2][lr + rr] = a.z; As[lk + 3][lr + rr] = a.w;
            float4 bb = *(const float4*)(base + (size_t)(c0 + lr + rr) * DD + kc + lk);
            Bs[lk + 0][lr + rr] = bb.x; Bs[lk + 1][lr + rr] = bb.y;
            Bs[lk + 2][lr + rr] = bb.z; Bs[lk + 3][lr + rr] = bb.w;
        }
        __syncthreads();
#pragma unroll
        for (int kk = 0; kk < KC; kk++) {
            float4 a0 = *(const float4*)&As[kk][ty * 8];
            float4 a1 = *(const float4*)&As[kk][ty * 8 + 4];
            float4 b0 = *(const float4*)&Bs[kk][tx * 8];
            float4 b1 = *(const float4*)&Bs[kk][tx * 8 + 4];
            float ar[8] = {a0.x, a0.y, a0.z, a0.w, a1.x, a1.y, a1.z, a1.w};
            float bc[8] = {b0.x, b0.y, b0.z, b0.w, b1.x, b1.y, b1.z, b1.w};
#pragma unroll
            for (int r = 0; r < 8; r++)
#pragma unroll
                for (int c = 0; c < 8; c++)
                    acc[r][c] = fmaf(ar[r], bc[c], acc[r][c]);
        }
        __syncthreads();
    }
    float* out = sim + (size_t)b * NN * NN;
#pragma unroll
    for (int r = 0; r < 8; r++) {
        int i = r0 + ty * 8 + r;
        bool rowv = i < len;
#pragma unroll
        for (int cg = 0; cg < 2; cg++) {
            int j0 = c0 + tx * 8 + cg * 4;
            float vv[4];
#pragma unroll
            for (int c = 0; c < 4; c++) {
                int j = j0 + c;
                float s = acc[r][cg * 4 + c] + (i == j ? 1.0f : 0.0f);
                vv[c] = (rowv && j < len) ? s : 0.0f;
            }
            float4 o;
            o.x = vv[0]; o.y = vv[1]; o.z = vv[2]; o.w = vv[3];
            *(float4*)(out + (size_t)i * NN + j0) = o;
        }
    }
}

// ---------------- kernel 3a: init v = mf ----------------
__global__ __launch_bounds__(256) void init_v(float* __restrict__ v,
                                              const int* __restrict__ lengths) {
    int i = blockIdx.x * 256 + threadIdx.x;
    int b = i >> 9, r = i & (NN - 1);
    v[i] = (r < max(lengths[b], 1)) ? 1.0f : 0.0f;
}

// ---------------- kernel 3: one Sinkhorn half-step (K symmetric) ----------
__global__ __launch_bounds__(256) void sink_kernel(const float* __restrict__ sim,
                                                   const float* __restrict__ xin,
                                                   float* __restrict__ xout,
                                                   const int* __restrict__ lengths) {
    __shared__ float4 vsh[NN / 4];
    int b = blockIdx.y;
    int len = max(lengths[b], 1);
    float nf = (float)len;
    int tid = threadIdx.x;
    if (tid < NN / 4) vsh[tid] = ((const float4*)(xin + (size_t)b * NN))[tid];
    __syncthreads();
    int w = tid >> 6, l = tid & 63;
    float4 va = vsh[2 * l], vb = vsh[2 * l + 1];
    int rbase = blockIdx.x * 64 + w * 16;
    const float* srow = sim + ((size_t)b * NN + rbase) * NN;
#pragma unroll 2
    for (int rr = 0; rr < 16; rr++) {
        const float* p = srow + (size_t)rr * NN + l * 8;
        float4 s0 = *(const float4*)p;
        float4 s1 = *(const float4*)(p + 4);
        float d = expf(2.0f * s0.x - 2.0f) * va.x;
        d = fmaf(expf(2.0f * s0.y - 2.0f), va.y, d);
        d = fmaf(expf(2.0f * s0.z - 2.0f), va.z, d);
        d = fmaf(expf(2.0f * s0.w - 2.0f), va.w, d);
        d = fmaf(expf(2.0f * s1.x - 2.0f), vb.x, d);
        d = fmaf(expf(2.0f * s1.y - 2.0f), vb.y, d);
        d = fmaf(expf(2.0f * s1.z - 2.0f), vb.z, d);
        d = fmaf(expf(2.0f * s1.w - 2.0f), vb.w, d);
#pragma unroll
        for (int m = 32; m; m >>= 1) d += __shfl_xor(d, m);
        if (l == 0) {
            int r = rbase + rr;
            float mu = (r < len) ? (1.0f / nf) : 0.0f;
            xout[(size_t)b * NN + r] = mu / (d + 1e-9f);
        }
    }
}

// ---------------- kernel 4: fused epilogue, in-place on d_out -------------
__global__ __launch_bounds__(256) void epi_kernel(float* __restrict__ io,
                                                  const float* __restrict__ u,
                                                  const float* __restrict__ v,
                                                  const int* __restrict__ lengths) {
    size_t idx = (size_t)blockIdx.x * 256 + threadIdx.x;  // float4 index
    int b = (int)(idx >> 16);
    int r = (int)(idx >> 7) & (NN - 1);
    int c4 = ((int)idx & 127) << 2;
    float4 s = ((float4*)io)[idx];
    float ui = u[(size_t)b * NN + r];
    float4 vv = *(const float4*)(v + (size_t)b * NN + c4);
    float nf = (float)max(lengths[b], 1);
    float t = nf * ui;
    float sv[4] = {s.x, s.y, s.z, s.w};
    float vj[4] = {vv.x, vv.y, vv.z, vv.w};
    float ov[4];
#pragma unroll
    for (int c = 0; c < 4; c++) {
        float sc = sv[c];
        float K = expf(2.0f * sc - 2.0f);
        float P = t * K * vj[c];
        if (P > 0.1f) {
            float x = fmaf(5.0f, sc, -5.0f);
            ov[c] = (x > 0.0f) ? (x + 1.0f) : expf(x);
        } else {
            ov[c] = 0.006737946999085467f;  // exp(-5)
        }
    }
    float4 o;
    o.x = ov[0]; o.y = ov[1]; o.z = ov[2]; o.w = ov[3];
    ((float4*)io)[idx] = o;
}

extern "C" void kernel_launch(void* const* d_in, const int* in_sizes, int n_in,
                              void* d_out, int out_size, void* d_ws, size_t ws_size,
                              hipStream_t stream) {
    const float* h = (const float*)d_in[0];
    const float* W0 = (const float*)d_in[1];
    const float* W1 = (const float*)d_in[2];
    const int* lengths = (const int*)d_in[3];
    float* sim = (float*)d_out;

    char* ws = (char*)d_ws;
    float* hn = (float*)ws;                              // 33.5 MB
    float* u = (float*)(ws + (size_t)BB * NN * DD * 4);  // 256 KB
    float* v = u + (size_t)BB * NN;                      // 256 KB

    hn_kernel<<<BB * NN / 4, 256, 0, stream>>>(h, W0, W1, hn);
    sim_kernel<<<dim3(NN / 128, NN / 128, BB), 256, 0, stream>>>(hn, lengths, sim);
    init_v<<<BB * NN / 256, 256, 0, stream>>>(v, lengths);
    for (int it = 0; it < 20; it++) {
        sink_kernel<<<dim3(NN / 64, BB), 256, 0, stream>>>(sim, v, u, lengths);
        sink_kernel<<<dim3(NN / 64, BB), 256, 0, stream>>>(sim, u, v, lengths);
    }
    epi_kernel<<<(unsigned)((size_t)BB * NN * NN / 4 / 256), 256, 0, stream>>>(sim, u, v, lengths);
}

// Round 2
// 733.045 us; speedup vs baseline: 1.6800x; 1.6800x over previous
//
#include <hip/hip_runtime.h>

#define BB 128
#define NN 512
#define DD 128

// ---------------- kernel 1: h -> normalized hn ----------------
__global__ __launch_bounds__(256) void hn_kernel(const float* __restrict__ h,
                                                 const float* __restrict__ W0,
                                                 const float* __restrict__ W1,
                                                 float* __restrict__ hn) {
    int wave = (int)((blockIdx.x * blockDim.x + threadIdx.x) >> 6);  // 0..B*N-1
    int lane = threadIdx.x & 63;
    const float2* h2 = (const float2*)(h + (size_t)wave * DD);
    float2 w0 = ((const float2*)W0)[lane];
    float2 w1 = ((const float2*)W1)[lane];
    float2 x = h2[lane];
    float p0 = fmaxf(x.x * w0.x, 0.0f) * w1.x;
    float p1 = fmaxf(x.y * w0.y, 0.0f) * w1.y;
    float ss = p0 * p0 + p1 * p1;
#pragma unroll
    for (int m = 32; m; m >>= 1) ss += __shfl_xor(ss, m);
    float inv = 1.0f / (sqrtf(ss) + 1e-12f);
    float2 o;
    o.x = p0 * inv;
    o.y = p1 * inv;
    ((float2*)(hn + (size_t)wave * DD))[lane] = o;
}

// ---------------- kernel 2: K = exp(2*(hn hn^T + eye) - 2) on valid region -
// 128x128 tile per block; tiles fully outside [0,len)^2 exit immediately.
// Thread columns: tx*4+[0..4) and 64+tx*4+[0..4)  (stride-4 LDS reads = 2-way
// bank aliasing, free on gfx950; old stride-8 was 4-way = 14.7M conflicts)
#define KC 32
__global__ __launch_bounds__(256) void sim_kernel(const float* __restrict__ hn,
                                                  const int* __restrict__ lengths,
                                                  float* __restrict__ K) {
    int b = blockIdx.z;
    int len = max(lengths[b], 1);
    int r0 = blockIdx.y * 128, c0 = blockIdx.x * 128;
    if (r0 >= len || c0 >= len) return;  // masked region: K stays unread garbage
    __shared__ float As[KC][132];
    __shared__ float Bs[KC][132];
    const float* base = hn + (size_t)b * NN * DD;
    int tid = threadIdx.x;
    int lr = tid >> 3;
    int lk = (tid & 7) << 2;
    int tx = tid & 15, ty = tid >> 4;
    float acc[8][8] = {};

    for (int kc = 0; kc < DD; kc += KC) {
#pragma unroll
        for (int rr = 0; rr < 128; rr += 32) {
            float4 a = *(const float4*)(base + (size_t)(r0 + lr + rr) * DD + kc + lk);
            As[lk + 0][lr + rr] = a.x; As[lk + 1][lr + rr] = a.y;
            As[lk + 2][lr + rr] = a.z; As[lk + 3][lr + rr] = a.w;
            float4 bb = *(const float4*)(base + (size_t)(c0 + lr + rr) * DD + kc + lk);
            Bs[lk + 0][lr + rr] = bb.x; Bs[lk + 1][lr + rr] = bb.y;
            Bs[lk + 2][lr + rr] = bb.z; Bs[lk + 3][lr + rr] = bb.w;
        }
        __syncthreads();
#pragma unroll
        for (int kk = 0; kk < KC; kk++) {
            float4 a0 = *(const float4*)&As[kk][ty * 8];
            float4 a1 = *(const float4*)&As[kk][ty * 8 + 4];
            float4 b0 = *(const float4*)&Bs[kk][tx * 4];
            float4 b1 = *(const float4*)&Bs[kk][64 + tx * 4];
            float ar[8] = {a0.x, a0.y, a0.z, a0.w, a1.x, a1.y, a1.z, a1.w};
            float bc[8] = {b0.x, b0.y, b0.z, b0.w, b1.x, b1.y, b1.z, b1.w};
#pragma unroll
            for (int r = 0; r < 8; r++)
#pragma unroll
                for (int c = 0; c < 8; c++)
                    acc[r][c] = fmaf(ar[r], bc[c], acc[r][c]);
        }
        __syncthreads();
    }
    float* out = K + (size_t)b * NN * NN;
#pragma unroll
    for (int r = 0; r < 8; r++) {
        int i = r0 + ty * 8 + r;
        if (i >= len) continue;
#pragma unroll
        for (int cg = 0; cg < 2; cg++) {
            int j0 = c0 + cg * 64 + tx * 4;
            if (j0 >= len) continue;  // tail floats past len within a stored
            float vv[4];              // float4 are garbage-but-finite, never read
#pragma unroll
            for (int c = 0; c < 4; c++) {
                float s = acc[r][cg * 4 + c] + ((i == j0 + c) ? 1.0f : 0.0f);
                vv[c] = expf(2.0f * s - 2.0f);
            }
            float4 o;
            o.x = vv[0]; o.y = vv[1]; o.z = vv[2]; o.w = vv[3];
            *(float4*)(out + (size_t)i * NN + j0) = o;
        }
    }
}

// ---------------- kernel 3a: init v = mf ----------------
__global__ __launch_bounds__(256) void init_v(float* __restrict__ v,
                                              const int* __restrict__ lengths) {
    int i = blockIdx.x * 256 + threadIdx.x;
    int b = i >> 9, r = i & (NN - 1);
    v[i] = (r < max(lengths[b], 1)) ? 1.0f : 0.0f;
}

// ---------------- kernel 3: one Sinkhorn half-step (K symmetric) ----------
// wg = 256 thr = 4 waves, each wave 8 rows => 32 rows/wg, grid (16, B).
// Lane l covers cols [4l,4l+4) and [256+4l,256+4l+4): contiguous float4s.
// Cols >= len: lane masked off (no fetch); tail-of-float4 garbage hits v_j=0.
__global__ __launch_bounds__(256) void sink_kernel(const float* __restrict__ K,
                                                   const float* __restrict__ xin,
                                                   float* __restrict__ xout,
                                                   const int* __restrict__ lengths) {
    int b = blockIdx.y;
    int len = max(lengths[b], 1);
    int rblk = blockIdx.x * 32;
    int tid = threadIdx.x;
    float* xo = xout + (size_t)b * NN;
    if (rblk >= len) {  // whole block masked: write zeros, no K traffic
        if (tid < 32) xo[rblk + tid] = 0.0f;
        return;
    }
    __shared__ float4 vsh[NN / 4];
    if (tid < NN / 4) vsh[tid] = ((const float4*)(xin + (size_t)b * NN))[tid];
    __syncthreads();
    int w = tid >> 6, l = tid & 63;
    float4 va = vsh[l];
    float4 vb = vsh[64 + l];
    bool c0ok = (4 * l) < len;
    bool c1ok = (256 + 4 * l) < len;
    float inv_n = 1.0f / (float)len;
    int r0 = rblk + w * 8;
    const float* Kr = K + ((size_t)b * NN + r0) * NN;
#pragma unroll
    for (int rr = 0; rr < 8; rr++) {
        int r = r0 + rr;
        float d = 0.0f;
        if (r < len) {
            const float* p = Kr + (size_t)rr * NN;
            if (c0ok) {
                float4 k0 = *(const float4*)(p + 4 * l);
                d = fmaf(k0.x, va.x, fmaf(k0.y, va.y, fmaf(k0.z, va.z, k0.w * va.w)));
            }
            if (c1ok) {
                float4 k1 = *(const float4*)(p + 256 + 4 * l);
                d = fmaf(k1.x, vb.x, fmaf(k1.y, vb.y, fmaf(k1.z, vb.z, fmaf(k1.w, vb.w, d))));
            }
        }
#pragma unroll
        for (int m = 32; m; m >>= 1) d += __shfl_xor(d, m);
        if (l == 0) xo[r] = (r < len) ? (inv_n / (d + 1e-9f)) : 0.0f;
    }
}

// ---------------- kernel 4: fused epilogue, in-place on d_out -------------
// P = n*u_i*K*v_j ; A = P>0.1 ; out = elu(2.5*lnK)+1 on A, exp(-5) elsewhere
__global__ __launch_bounds__(256) void epi_kernel(float* __restrict__ io,
                                                  const float* __restrict__ u,
                                                  const float* __restrict__ v,
                                                  const int* __restrict__ lengths) {
    const float E5 = 0.006737946999085467f;  // exp(-5)
    size_t idx = (size_t)blockIdx.x * 256 + threadIdx.x;  // float4 index
    int b = (int)(idx >> 16);
    int r = (int)(idx >> 7) & (NN - 1);
    int c4 = ((int)idx & 127) << 2;
    int len = max(lengths[b], 1);
    float4 o;
    if (r >= len || c4 >= len) {  // masked: constant, no K read
        o.x = E5; o.y = E5; o.z = E5; o.w = E5;
        ((float4*)io)[idx] = o;
        return;
    }
    float4 k = ((float4*)io)[idx];
    float ui = u[(size_t)b * NN + r];
    float4 vv = *(const float4*)(v + (size_t)b * NN + c4);
    float t = (float)len * ui;
    float kv[4] = {k.x, k.y, k.z, k.w};
    float vj[4] = {vv.x, vv.y, vv.z, vv.w};
    float ov[4];
#pragma unroll
    for (int c = 0; c < 4; c++) {
        float Kc = kv[c];
        float P = t * Kc * vj[c];
        bool valid = (c4 + c) < len;
        if (valid && P > 0.1f) {
            float x = 2.5f * logf(Kc);  // == 5*sim - 5
            ov[c] = (x > 0.0f) ? (x + 1.0f) : expf(x);
        } else {
            ov[c] = E5;
        }
    }
    o.x = ov[0]; o.y = ov[1]; o.z = ov[2]; o.w = ov[3];
    ((float4*)io)[idx] = o;
}

extern "C" void kernel_launch(void* const* d_in, const int* in_sizes, int n_in,
                              void* d_out, int out_size, void* d_ws, size_t ws_size,
                              hipStream_t stream) {
    const float* h = (const float*)d_in[0];
    const float* W0 = (const float*)d_in[1];
    const float* W1 = (const float*)d_in[2];
    const int* lengths = (const int*)d_in[3];
    float* K = (float*)d_out;  // [B,N,N]: holds K, overwritten by epilogue

    char* ws = (char*)d_ws;
    float* hn = (float*)ws;                              // 33.5 MB
    float* u = (float*)(ws + (size_t)BB * NN * DD * 4);  // 256 KB
    float* v = u + (size_t)BB * NN;                      // 256 KB

    hn_kernel<<<BB * NN / 4, 256, 0, stream>>>(h, W0, W1, hn);
    sim_kernel<<<dim3(NN / 128, NN / 128, BB), 256, 0, stream>>>(hn, lengths, K);
    init_v<<<BB * NN / 256, 256, 0, stream>>>(v, lengths);
    for (int it = 0; it < 20; it++) {
        sink_kernel<<<dim3(NN / 32, BB), 256, 0, stream>>>(K, v, u, lengths);
        sink_kernel<<<dim3(NN / 32, BB), 256, 0, stream>>>(K, u, v, lengths);
    }
    epi_kernel<<<(unsigned)((size_t)BB * NN * NN / 4 / 256), 256, 0, stream>>>(K, u, v, lengths);
}